// Round 6
// baseline (1393.958 us; speedup 1.0000x reference)
//
#include <hip/hip_runtime.h>
#include <hip/hip_bf16.h>
#include <hip/hip_fp16.h>

#define SEQ   320
#define GATES 1600
#define NCOL  3200
#define GDW   16    // workgroups per direction in the recurrent kernel
#define RPW   25    // h-rows owned per workgroup (400/16)
#define EXN   163840 // dwords per exchange plane (2*16*320*16)

typedef _Float16 half2v __attribute__((ext_vector_type(2)));
typedef _Float16 f16x8  __attribute__((ext_vector_type(8)));
typedef float    f32x4  __attribute__((ext_vector_type(4)));
union H2U { unsigned u; half2v h; __half2 hh; };

// ---------------------------------------------------------------- prep: embed->f16, bias sums, cvt W_ih_l0
__global__ __launch_bounds__(256) void prep_kernel(
    const int* __restrict__ words, const int* __restrict__ tags,
    const float* __restrict__ wemb, const float* __restrict__ temb,
    _Float16* __restrict__ Ah0,
    const float* __restrict__ bihl0,  const float* __restrict__ bhhl0,
    const float* __restrict__ bihl0r, const float* __restrict__ bhhl0r,
    const float* __restrict__ bihl1,  const float* __restrict__ bhhl1,
    const float* __restrict__ bihl1r, const float* __restrict__ bhhl1r,
    const float* __restrict__ mlpb1,
    float* __restrict__ bL0, float* __restrict__ bL1, float* __restrict__ bAB,
    const float* __restrict__ wih0, const float* __restrict__ wih0r,
    _Float16* __restrict__ BhA)
{
    const int b = blockIdx.x, t = threadIdx.x;
    if (b < 520) {                       // embeddings -> Ah0 (320 x 416, zero-pad)
        int i = b * 256 + t;
        if (i >= SEQ * 416) return;
        int tt = i / 416, c = i % 416;
        float v = 0.f;
        if (c < 300)      v = wemb[(size_t)words[tt] * 300 + c];
        else if (c < 400) v = temb[(size_t)tags[tt] * 100 + (c - 300)];
        Ah0[i] = (_Float16)v;
    } else if (b < 533) {                // bias sums
        int g = (b - 520) * 256 + t;
        if (g >= NCOL) return;
        if (g < GATES) {
            bL0[g] = bihl0[g] + bhhl0[g];
            bL1[g] = bihl1[g] + bhhl1[g];
            bAB[g] = mlpb1[g];
        } else {
            int q = g - GATES;
            bL0[g] = bihl0r[q] + bhhl0r[q];
            bL1[g] = bihl1r[q] + bhhl1r[q];
            bAB[g] = 0.f;
        }
    } else {                             // W_ih_l0 -> fp16 (3200 x 416, zero-pad K)
        int i = (b - 533) * 256 + t;
        if (i >= NCOL * 416) return;
        int n = i / 416, k = i % 416;
        float v = 0.f;
        if (k < 400)
            v = (n < GATES) ? wih0[(size_t)n * 400 + k]
                            : wih0r[(size_t)(n - GATES) * 400 + k];
        BhA[i] = (_Float16)v;
    }
}

// ---------------------------------------------------------------- cvt W_ih_l1 -> BhB, mlp_w1 -> BhA
__global__ __launch_bounds__(256) void cvt2_kernel(
    const float* __restrict__ wih1, const float* __restrict__ wih1r,
    _Float16* __restrict__ BhB,
    const float* __restrict__ mlpw1, _Float16* __restrict__ BhA)
{
    const int b = blockIdx.x, t = threadIdx.x;
    if (b < 10000) {
        int i = b * 256 + t;
        if (i >= NCOL * 800) return;
        int n = i / 800, k = i % 800;
        BhB[i] = (_Float16)((n < GATES) ? wih1[(size_t)n * 800 + k]
                                        : wih1r[(size_t)(n - GATES) * 800 + k]);
    } else {
        int i = (b - 10000) * 256 + t;
        if (i >= NCOL * 800) return;
        int n = i / 800, k = i % 800;
        BhA[i] = (_Float16)((n < GATES) ? mlpw1[(size_t)n * 1600 + k]
                                        : mlpw1[(size_t)(n - GATES) * 1600 + 800 + k]);
    }
}

// ---------------------------------------------------------------- MFMA f16 GEMM (as R6, verified)
__global__ __launch_bounds__(256) void gemm_f16(
    const _Float16* __restrict__ A, int Kp,
    const _Float16* __restrict__ B,
    const float* __restrict__ bias, float* __restrict__ C)
{
    const int tid  = threadIdx.x;
    const int w    = tid >> 6, lane = tid & 63;
    const int quad = lane >> 4, l16 = lane & 15;
    const int mb   = blockIdx.y * 32 + (w & 1) * 16;
    const int n0   = blockIdx.x * 64 + (w >> 1) * 32;
    const _Float16* Arow = A + (size_t)(mb + l16) * Kp + quad * 8;
    const _Float16* B0r  = B + (size_t)(n0 + l16) * Kp + quad * 8;
    const _Float16* B1r  = B0r + (size_t)16 * Kp;
    f32x4 acc0 = {0.f, 0.f, 0.f, 0.f}, acc1 = {0.f, 0.f, 0.f, 0.f};
#pragma unroll 4
    for (int k0 = 0; k0 < Kp; k0 += 32) {
        f16x8 a  = *(const f16x8*)(Arow + k0);
        f16x8 b0 = *(const f16x8*)(B0r + k0);
        f16x8 b1 = *(const f16x8*)(B1r + k0);
        acc0 = __builtin_amdgcn_mfma_f32_16x16x32_f16(a, b0, acc0, 0, 0, 0);
        acc1 = __builtin_amdgcn_mfma_f32_16x16x32_f16(a, b1, acc1, 0, 0, 0);
    }
    const int mr = mb + quad * 4;
    float bn0 = bias[n0 + l16], bn1 = bias[n0 + 16 + l16];
#pragma unroll
    for (int r = 0; r < 4; ++r) {
        C[(size_t)(mr + r) * NCOL + n0 + l16]      = acc0[r] + bn0;
        C[(size_t)(mr + r) * NCOL + n0 + 16 + l16] = acc1[r] + bn1;
    }
}

// ---------------------------------------------------------------- recurrence
// R13 = R12 with exactly ONE change: the poll loop is fast-dominant.
// R12 issued the slow (device-scope/MALL) load and the fast (sc0/L2) load
// every iteration and drained both with vmcnt(0), so the iteration period
// was gated by the MALL RTT (~600-900 cy) even when the data sat in the
// local L2. Now the tight loop is fast-plane only (~L2 RTT per iteration);
// the slow plane is checked every 4th iteration purely as the cross-XCD
// correctness fallback. Everything else identical to R12:
// (1) XCD placement: grid=128, real WGs at blockIdx%8<2 (dir=bid%8,
//     wg=bid>>3) -> each direction's 16 WGs share one XCD (heuristic).
// (2) Dual-path exchange: agent-scope store to ex_slow (MALL) + plain
//     store to ex_fast (local L2); consumer polls fast via sc0 load.
// (3) Pollers at tid 64..271 (waves 1-4), freeing wave 0 for act.
__global__ __launch_bounds__(1024, 4) void lstm_layer(
    const float* __restrict__ gates,   // SEQ x 3200 (x@W_ih^T + biases)
    const float* __restrict__ whh_f, const float* __restrict__ whh_b,
    const float* __restrict__ h0f, const float* __restrict__ h0b,
    const float* __restrict__ c0f, const float* __restrict__ c0b,
    unsigned* __restrict__ ex,         // [0,EXN): slow plane, [EXN,2*EXN): fast plane
    _Float16* __restrict__ ah)         // SEQ x 800 fp16 h (input to next GEMM)
{
    const int bid = blockIdx.x;
    if ((bid & 7) >= 2) return;        // dummy WG (placement trick)
    const int dir = bid & 7;           // 0 or 1
    const int wg  = bid >> 3;          // 0..15

    __shared__ unsigned h_pk[200];     // 400 halfs of h_prev
    __shared__ float part[16][28];
    unsigned short* hs = (unsigned short*)h_pk;
    const int tid = threadIdx.x;
    const int j0  = wg * RPW;
    const float* whh = dir ? whh_b : whh_f;
    const float* h0d = dir ? h0b : h0f;
    const float* c0d = dir ? c0b : c0f;

    const int w    = tid >> 6;         // wave 0..15
    const int lane = tid & 63;
    const int g    = w & 3;            // gate
    const int kq   = w >> 2;           // k-quarter (100 elems)
    const int half = lane & 1;         // k-split within quarter
    const int r    = lane >> 1;        // row within WG (active if r<25)
    const int jrow = j0 + (r < RPW ? r : RPW - 1);

    // one-time: 52 W_hh weights/thread, fp16-packed into 26 uints (spill-proof)
    unsigned wr[26];
    {
        const float2* wp = (const float2*)(whh + (size_t)(g * 400 + jrow) * 400 +
                                           kq * 100 + 48 * half);
#pragma unroll
        for (int i = 0; i < 26; ++i) {
            H2U cv; float2 f = wp[i];
            cv.hh = __floats2half2_rn(f.x, f.y);
            wr[i] = (half == 0 && i >= 24) ? 0u : cv.u;
        }
    }

    // pollers: tid 64..271 (waves 1-4), 16 producers x 13 dwords
    const bool is_poller = (tid >= 64 && tid < 272);
    const int pp = (tid - 64) / 13;    // producer block polled
    const int pd = (tid - 64) % 13;    // dword within block
    float c_prev = (tid < RPW) ? c0d[j0 + tid] : 0.f;

    for (int s = 0; s < 320; ++s) {
        const int row = dir ? (319 - s) : s;

        // gate prefetch (independent of h_prev, overlaps the poll)
        float gv0 = 0.f, gv1 = 0.f, gv2 = 0.f, gv3 = 0.f;
        if (tid < RPW) {
            const float* gx = gates + (size_t)row * NCOL + dir * GATES + j0 + tid;
            gv0 = gx[0]; gv1 = gx[400]; gv2 = gx[800]; gv3 = gx[1200];
        }

        if (s == 0) {
            if (tid < 100) {
                float4 f = ((const float4*)h0d)[tid];
                H2U a, b;
                a.hh = __floats2half2_rn(f.x, f.y);
                b.hh = __floats2half2_rn(f.z, f.w);
                ((uint2*)h_pk)[tid] = make_uint2(a.u, b.u);
            }
        } else if (is_poller && pp != wg) {
            const int rp = dir ? (row + 1) : (row - 1);
            const size_t off = (((size_t)dir * GDW + pp) * SEQ + rp) * 16 + pd;
            const unsigned* srcS = ex + off;
            const unsigned* srcF = ex + EXN + off;
            unsigned v;
            for (int it = 0; ; ++it) {
                // fast path: XCD-local L2 read (sc0 bypasses L1), ~L2 RTT
                unsigned vf;
                asm volatile("global_load_dword %0, %1, off sc0\n\t"
                             "s_waitcnt vmcnt(0)"
                             : "=v"(vf) : "v"(srcF) : "memory");
                if ((vf & 0xFFFFu) != 0xFFFFu &&
                    (pd == 12 || (vf >> 16) != 0xFFFFu)) { v = vf; break; }
                // slow path every 4th iter: cross-XCD correctness fallback
                if ((it & 3) == 3) {
                    unsigned vs = __hip_atomic_load(srcS, __ATOMIC_RELAXED,
                                                    __HIP_MEMORY_SCOPE_AGENT);
                    if ((vs & 0xFFFFu) != 0xFFFFu &&
                        (pd == 12 || (vs >> 16) != 0xFFFFu)) { v = vs; break; }
                }
            }
            const int hb = pp * RPW + pd * 2;
            hs[hb] = (unsigned short)(v & 0xFFFFu);
            if (pd < 12) hs[hb + 1] = (unsigned short)(v >> 16);
        }
        // barrier 1: LDS-only drain (no vmcnt)
        asm volatile("s_waitcnt lgkmcnt(0)" ::: "memory");
        __builtin_amdgcn_s_barrier();

        // partial dot: 52 halves via 13 ds_read_b64 + 26 v_dot2_f32_f16
        {
            const uint2* hp2 = (const uint2*)h_pk + kq * 25 + 12 * half;
            float acc = 0.f;
#pragma unroll
            for (int i = 0; i < 13; ++i) {
                uint2 hv2 = hp2[i];
                H2U w0, w1, x0, x1;
                w0.u = wr[2 * i]; w1.u = wr[2 * i + 1];
                x0.u = hv2.x;     x1.u = hv2.y;
                acc = __builtin_amdgcn_fdot2(w0.h, x0.h, acc, false);
                acc = __builtin_amdgcn_fdot2(w1.h, x1.h, acc, false);
            }
            acc += __shfl_xor(acc, 1, 64);
            if (half == 0 && r < RPW) part[w][r] = acc;
        }
        // barrier 2: LDS-only drain
        asm volatile("s_waitcnt lgkmcnt(0)" ::: "memory");
        __builtin_amdgcn_s_barrier();

        // activation + exchange store (wave 0 only)
        float hv = 0.f;
        if (tid < RPW) {
            float gi = gv0 + ((part[0][tid] + part[4][tid]) + (part[8][tid]  + part[12][tid]));
            float gf = gv1 + ((part[1][tid] + part[5][tid]) + (part[9][tid]  + part[13][tid]));
            float gg = gv2 + ((part[2][tid] + part[6][tid]) + (part[10][tid] + part[14][tid]));
            float go = gv3 + ((part[3][tid] + part[7][tid]) + (part[11][tid] + part[15][tid]));
            float iv = 1.f / (1.f + __expf(-gi));
            float fv = 1.f / (1.f + __expf(-gf));
            float ov = 1.f / (1.f + __expf(-go));
            float tg = 1.f - 2.f / (1.f + __expf(2.f * gg));
            c_prev = fv * c_prev + iv * tg;
            float tc = 1.f - 2.f / (1.f + __expf(2.f * c_prev));
            hv = ov * tc;
        }
        if (w == 0) {
            int i0 = 2 * lane     < 63 ? 2 * lane     : 63;
            int i1 = 2 * lane + 1 < 63 ? 2 * lane + 1 : 63;
            float xlo = __shfl(hv, i0, 64);
            float xhi = __shfl(hv, i1, 64);
            if (lane < 13) {                 // one private 64B line per step, dual-plane
                H2U pk;
                pk.hh = __floats2half2_rn(xlo, (2 * lane + 1 < RPW) ? xhi : 0.f);
                const size_t off = (((size_t)dir * GDW + wg) * SEQ + row) * 16 + lane;
                __hip_atomic_store(ex + off, pk.u,
                                   __ATOMIC_RELAXED, __HIP_MEMORY_SCOPE_AGENT);
                ex[EXN + off] = pk.u;        // plain store -> local L2 (fast plane)
            }
            if (tid < RPW) {                 // fp16 h for next GEMM + own-row LDS
                ah[(size_t)row * 800 + dir * 400 + j0 + tid] = (_Float16)hv;
                H2U o; o.hh = __floats2half2_rn(hv, 0.f);
                hs[RPW * wg + tid] = (unsigned short)(o.u & 0xFFFFu);
            }
        }
        // hazards: identical to R11/R12 (poll/act writes vs dot reads separated
        // by the two lgkmcnt-drained barriers; disjoint LDS ranges). safe.
    }
}

// ---------------------------------------------------------------- fused scorer (+ border rows)
__global__ __launch_bounds__(256) void scores_kernel(
    const float* __restrict__ ab, const float* __restrict__ w2,
    const float* __restrict__ b2, float* __restrict__ out)
{
    if (blockIdx.y == 20) {              // border: row 0 / col 0
        int i = blockIdx.x * 256 + threadIdx.y * 16 + threadIdx.x;
        if (blockIdx.x < 2 && i < 321) {
            out[i]               = (i == 0) ? 1.f : 0.f;
            out[(size_t)i * 321] = (i == 0) ? 1.f : 0.f;
        }
        return;
    }
    __shared__ float a_s[16 * 132];
    __shared__ float b_s[16 * 132];
    __shared__ float w_s[128];
    const int tx = threadIdx.x, ty = threadIdx.y;
    const int tid = ty * 16 + tx;
    const int n0 = blockIdx.y * 16, d0 = blockIdx.x * 16;
    float acc = 0.f;
    for (int kc = 0; kc < 1600; kc += 128) {
        for (int i = tid; i < 16 * 128; i += 256) {
            int r = i >> 7, c = i & 127;
            a_s[r * 132 + c] = ab[(size_t)(n0 + r) * NCOL + kc + c];
            b_s[r * 132 + c] = ab[(size_t)(d0 + r) * NCOL + 1600 + kc + c];
        }
        if (tid < 128) w_s[tid] = w2[kc + tid];
        __syncthreads();
#pragma unroll
        for (int k = 0; k < 128; k += 4) {
            float4 av = *(const float4*)&a_s[ty * 132 + k];
            float4 bv = *(const float4*)&b_s[tx * 132 + k];
            float4 wv = *(const float4*)&w_s[k];
            acc += fmaxf(av.x + bv.x, 0.f) * wv.x;
            acc += fmaxf(av.y + bv.y, 0.f) * wv.y;
            acc += fmaxf(av.z + bv.z, 0.f) * wv.z;
            acc += fmaxf(av.w + bv.w, 0.f) * wv.w;
        }
        __syncthreads();
    }
    int n = n0 + ty, d = d0 + tx;
    out[(size_t)(n + 1) * 321 + (d + 1)] = (n == d) ? 0.f : (acc + b2[0]);
}

// ---------------------------------------------------------------- launcher
extern "C" void kernel_launch(void* const* d_in, const int* in_sizes, int n_in,
                              void* d_out, int out_size, void* d_ws, size_t ws_size,
                              hipStream_t stream)
{
    const int*   words    = (const int*)d_in[0];
    const int*   tags     = (const int*)d_in[1];
    const float* wemb     = (const float*)d_in[3];
    const float* temb     = (const float*)d_in[4];
    const float* h0       = (const float*)d_in[5];
    const float* c0       = (const float*)d_in[6];
    const float* w_ih_l0  = (const float*)d_in[7];
    const float* w_hh_l0  = (const float*)d_in[8];
    const float* b_ih_l0  = (const float*)d_in[9];
    const float* b_hh_l0  = (const float*)d_in[10];
    const float* w_ih_l0r = (const float*)d_in[11];
    const float* w_hh_l0r = (const float*)d_in[12];
    const float* b_ih_l0r = (const float*)d_in[13];
    const float* b_hh_l0r = (const float*)d_in[14];
    const float* w_ih_l1  = (const float*)d_in[15];
    const float* w_hh_l1  = (const float*)d_in[16];
    const float* b_ih_l1  = (const float*)d_in[17];
    const float* b_hh_l1  = (const float*)d_in[18];
    const float* w_ih_l1r = (const float*)d_in[19];
    const float* w_hh_l1r = (const float*)d_in[20];
    const float* b_ih_l1r = (const float*)d_in[21];
    const float* b_hh_l1r = (const float*)d_in[22];
    const float* mlp_w1   = (const float*)d_in[23];
    const float* mlp_b1   = (const float*)d_in[24];
    const float* mlp_w2   = (const float*)d_in[25];
    const float* mlp_b2   = (const float*)d_in[26];
    float* out = (float*)d_out;

    float* ws      = (float*)d_ws;
    float*    gates  = ws;                              // 320*3200 = 1,024,000 f32
    float*    biasL0 = ws + 1024000;
    float*    biasL1 = ws + 1027200;
    float*    biasAB = ws + 1030400;
    unsigned* ex     = (unsigned*)(ws + 1033600);       // slow+fast planes, 327,680 u32
    _Float16* Ah0    = (_Float16*)(ws + 1361280);       // 320*416 halves
    _Float16* Ah1    = (_Float16*)(ws + 1427840);       // 320*800 halves
    _Float16* Ah2    = (_Float16*)(ws + 1555840);       // 320*800 halves
    _Float16* BhA    = (_Float16*)(ws + 1683840);       // up to 3200*800 halves
    _Float16* BhB    = (_Float16*)(ws + 2963840);       // 3200*800 halves

    // sentinel-fill both exchange planes (data doubles as ready flag)
    hipMemsetAsync(ex, 0xFF, 327680u * 4, stream);

    prep_kernel<<<5733, 256, 0, stream>>>(
        words, tags, wemb, temb, Ah0,
        b_ih_l0, b_hh_l0, b_ih_l0r, b_hh_l0r,
        b_ih_l1, b_hh_l1, b_ih_l1r, b_hh_l1r,
        mlp_b1, biasL0, biasL1, biasAB, w_ih_l0, w_ih_l0r, BhA);

    gemm_f16<<<dim3(50, 10), 256, 0, stream>>>(Ah0, 416, BhA, biasL0, gates);
    cvt2_kernel<<<20000, 256, 0, stream>>>(w_ih_l1, w_ih_l1r, BhB, mlp_w1, BhA);
    lstm_layer<<<128, 1024, 0, stream>>>(gates, w_hh_l0, w_hh_l0r,
                                         h0, h0 + 400, c0, c0 + 400, ex, Ah1);
    // re-sentinel both planes for layer 1 (stream-ordered after lstm L0)
    hipMemsetAsync(ex, 0xFF, 327680u * 4, stream);
    gemm_f16<<<dim3(50, 10), 256, 0, stream>>>(Ah1, 800, BhB, biasL1, gates);
    lstm_layer<<<128, 1024, 0, stream>>>(gates, w_hh_l1, w_hh_l1r,
                                         h0 + 800, h0 + 1200, c0 + 800, c0 + 1200,
                                         ex, Ah2);
    gemm_f16<<<dim3(50, 10), 256, 0, stream>>>(Ah2, 800, BhA, biasAB, gates);

    scores_kernel<<<dim3(20, 21), dim3(16, 16), 0, stream>>>(gates, mlp_w2, mlp_b2, out);
}

// Round 7
// 1364.008 us; speedup vs baseline: 1.0220x; 1.0220x over previous
//
#include <hip/hip_runtime.h>
#include <hip/hip_bf16.h>
#include <hip/hip_fp16.h>

#define SEQ   320
#define GATES 1600
#define NCOL  3200
#define GDW   16    // workgroups per direction in the recurrent kernel
#define RPW   25    // h-rows owned per workgroup (400/16)

typedef _Float16 half2v __attribute__((ext_vector_type(2)));
typedef _Float16 f16x8  __attribute__((ext_vector_type(8)));
typedef float    f32x4  __attribute__((ext_vector_type(4)));
union H2U { unsigned u; half2v h; __half2 hh; };

// 4-deep staggered device-scope poll ring. Loads from one address are kept
// 4-in-flight, ~128cy apart (s_sleep 2 stagger), checked oldest-first with
// s_waitcnt vmcnt(3) -- sampling cadence ~RTT/4 instead of RTT. Per-lane
// exit via exec-mask peeling; exec restored at the end. Slots are "+v" so
// they stay live (reserved) across the whole step loop -- stray in-flight
// loads can only ever write these registers. Sentinel: a written dword is
// one atomic u32 store of two finite fp16 (never 0xFFFFFFFF).
#define POLL_RING(SA, SB, SC, SD)                                           \
    asm volatile(                                                           \
        "global_load_dword %[a], %[ad], off sc0 sc1\n\t"                    \
        "s_sleep 2\n\t"                                                     \
        "global_load_dword %[b], %[ad], off sc0 sc1\n\t"                    \
        "s_sleep 2\n\t"                                                     \
        "global_load_dword %[c], %[ad], off sc0 sc1\n\t"                    \
        "s_sleep 2\n\t"                                                     \
        "global_load_dword %[d], %[ad], off sc0 sc1\n\t"                    \
        "s_mov_b64 %[ex], exec\n\t"                                         \
        "Lp%=:\n\t"                                                         \
        "s_waitcnt vmcnt(3)\n\t"                                            \
        "v_mov_b32 %[r], %[a]\n\t"                                          \
        "global_load_dword %[a], %[ad], off sc0 sc1\n\t"                    \
        "v_cmp_ne_u32 vcc, -1, %[r]\n\t"                                    \
        "s_andn2_b64 exec, exec, vcc\n\t"                                   \
        "s_cbranch_execz Ld%=\n\t"                                          \
        "s_waitcnt vmcnt(3)\n\t"                                            \
        "v_mov_b32 %[r], %[b]\n\t"                                          \
        "global_load_dword %[b], %[ad], off sc0 sc1\n\t"                    \
        "v_cmp_ne_u32 vcc, -1, %[r]\n\t"                                    \
        "s_andn2_b64 exec, exec, vcc\n\t"                                   \
        "s_cbranch_execz Ld%=\n\t"                                          \
        "s_waitcnt vmcnt(3)\n\t"                                            \
        "v_mov_b32 %[r], %[c]\n\t"                                          \
        "global_load_dword %[c], %[ad], off sc0 sc1\n\t"                    \
        "v_cmp_ne_u32 vcc, -1, %[r]\n\t"                                    \
        "s_andn2_b64 exec, exec, vcc\n\t"                                   \
        "s_cbranch_execz Ld%=\n\t"                                          \
        "s_waitcnt vmcnt(3)\n\t"                                            \
        "v_mov_b32 %[r], %[d]\n\t"                                          \
        "global_load_dword %[d], %[ad], off sc0 sc1\n\t"                    \
        "v_cmp_ne_u32 vcc, -1, %[r]\n\t"                                    \
        "s_andn2_b64 exec, exec, vcc\n\t"                                   \
        "s_cbranch_execz Ld%=\n\t"                                          \
        "s_branch Lp%=\n\t"                                                 \
        "Ld%=:\n\t"                                                         \
        "s_mov_b64 exec, %[ex]\n\t"                                         \
        : [a] "+v"(SA), [b] "+v"(SB), [c] "+v"(SC), [d] "+v"(SD),           \
          [r] "=&v"(res), [ex] "=&s"(execsave)                              \
        : [ad] "v"(srcS)                                                    \
        : "vcc", "memory")

// ---------------------------------------------------------------- prep: embed->f16, bias sums, cvt W_ih_l0
__global__ __launch_bounds__(256) void prep_kernel(
    const int* __restrict__ words, const int* __restrict__ tags,
    const float* __restrict__ wemb, const float* __restrict__ temb,
    _Float16* __restrict__ Ah0,
    const float* __restrict__ bihl0,  const float* __restrict__ bhhl0,
    const float* __restrict__ bihl0r, const float* __restrict__ bhhl0r,
    const float* __restrict__ bihl1,  const float* __restrict__ bhhl1,
    const float* __restrict__ bihl1r, const float* __restrict__ bhhl1r,
    const float* __restrict__ mlpb1,
    float* __restrict__ bL0, float* __restrict__ bL1, float* __restrict__ bAB,
    const float* __restrict__ wih0, const float* __restrict__ wih0r,
    _Float16* __restrict__ BhA)
{
    const int b = blockIdx.x, t = threadIdx.x;
    if (b < 520) {                       // embeddings -> Ah0 (320 x 416, zero-pad)
        int i = b * 256 + t;
        if (i >= SEQ * 416) return;
        int tt = i / 416, c = i % 416;
        float v = 0.f;
        if (c < 300)      v = wemb[(size_t)words[tt] * 300 + c];
        else if (c < 400) v = temb[(size_t)tags[tt] * 100 + (c - 300)];
        Ah0[i] = (_Float16)v;
    } else if (b < 533) {                // bias sums
        int g = (b - 520) * 256 + t;
        if (g >= NCOL) return;
        if (g < GATES) {
            bL0[g] = bihl0[g] + bhhl0[g];
            bL1[g] = bihl1[g] + bhhl1[g];
            bAB[g] = mlpb1[g];
        } else {
            int q = g - GATES;
            bL0[g] = bihl0r[q] + bhhl0r[q];
            bL1[g] = bihl1r[q] + bhhl1r[q];
            bAB[g] = 0.f;
        }
    } else {                             // W_ih_l0 -> fp16 (3200 x 416, zero-pad K)
        int i = (b - 533) * 256 + t;
        if (i >= NCOL * 416) return;
        int n = i / 416, k = i % 416;
        float v = 0.f;
        if (k < 400)
            v = (n < GATES) ? wih0[(size_t)n * 400 + k]
                            : wih0r[(size_t)(n - GATES) * 400 + k];
        BhA[i] = (_Float16)v;
    }
}

// ---------------------------------------------------------------- cvt W_ih_l1 -> BhB, mlp_w1 -> BhA
__global__ __launch_bounds__(256) void cvt2_kernel(
    const float* __restrict__ wih1, const float* __restrict__ wih1r,
    _Float16* __restrict__ BhB,
    const float* __restrict__ mlpw1, _Float16* __restrict__ BhA)
{
    const int b = blockIdx.x, t = threadIdx.x;
    if (b < 10000) {
        int i = b * 256 + t;
        if (i >= NCOL * 800) return;
        int n = i / 800, k = i % 800;
        BhB[i] = (_Float16)((n < GATES) ? wih1[(size_t)n * 800 + k]
                                        : wih1r[(size_t)(n - GATES) * 800 + k]);
    } else {
        int i = (b - 10000) * 256 + t;
        if (i >= NCOL * 800) return;
        int n = i / 800, k = i % 800;
        BhA[i] = (_Float16)((n < GATES) ? mlpw1[(size_t)n * 1600 + k]
                                        : mlpw1[(size_t)(n - GATES) * 1600 + 800 + k]);
    }
}

// ---------------------------------------------------------------- MFMA f16 GEMM (as R6, verified)
__global__ __launch_bounds__(256) void gemm_f16(
    const _Float16* __restrict__ A, int Kp,
    const _Float16* __restrict__ B,
    const float* __restrict__ bias, float* __restrict__ C)
{
    const int tid  = threadIdx.x;
    const int w    = tid >> 6, lane = tid & 63;
    const int quad = lane >> 4, l16 = lane & 15;
    const int mb   = blockIdx.y * 32 + (w & 1) * 16;
    const int n0   = blockIdx.x * 64 + (w >> 1) * 32;
    const _Float16* Arow = A + (size_t)(mb + l16) * Kp + quad * 8;
    const _Float16* B0r  = B + (size_t)(n0 + l16) * Kp + quad * 8;
    const _Float16* B1r  = B0r + (size_t)16 * Kp;
    f32x4 acc0 = {0.f, 0.f, 0.f, 0.f}, acc1 = {0.f, 0.f, 0.f, 0.f};
#pragma unroll 4
    for (int k0 = 0; k0 < Kp; k0 += 32) {
        f16x8 a  = *(const f16x8*)(Arow + k0);
        f16x8 b0 = *(const f16x8*)(B0r + k0);
        f16x8 b1 = *(const f16x8*)(B1r + k0);
        acc0 = __builtin_amdgcn_mfma_f32_16x16x32_f16(a, b0, acc0, 0, 0, 0);
        acc1 = __builtin_amdgcn_mfma_f32_16x16x32_f16(a, b1, acc1, 0, 0, 0);
    }
    const int mr = mb + quad * 4;
    float bn0 = bias[n0 + l16], bn1 = bias[n0 + 16 + l16];
#pragma unroll
    for (int r = 0; r < 4; ++r) {
        C[(size_t)(mr + r) * NCOL + n0 + l16]      = acc0[r] + bn0;
        C[(size_t)(mr + r) * NCOL + n0 + 16 + l16] = acc1[r] + bn1;
    }
}

// ---------------------------------------------------------------- recurrence
// R14 = R12 with the exchange simplified to ONE (device-scope) plane and the
// poll loop replaced by the 4-deep staggered ring (POLL_RING above).
// Evidence through R13 says the fast plane never delivered (placement or
// mechanism), and discovery was quantized at one MALL RTT (~900cy) because
// each slow poll was issued+drained serially. The ring samples the same
// address at ~RTT/4 cadence with counted vmcnt(3) -- never draining to 0 in
// the loop. Two register banks alternate by step parity so stray in-flight
// loads from step s can never corrupt step s+1 (they land in the idle bank).
// Kept from R12: XCD placement trick (grid=128, real WGs at bid%8<2),
// pollers on waves 1-4 (tid 64..271), lgkmcnt-only barriers.
__global__ __launch_bounds__(1024, 4) void lstm_layer(
    const float* __restrict__ gates,   // SEQ x 3200 (x@W_ih^T + biases)
    const float* __restrict__ whh_f, const float* __restrict__ whh_b,
    const float* __restrict__ h0f, const float* __restrict__ h0b,
    const float* __restrict__ c0f, const float* __restrict__ c0b,
    unsigned* __restrict__ ex,         // exchange plane (re-sentineled per layer)
    _Float16* __restrict__ ah)         // SEQ x 800 fp16 h (input to next GEMM)
{
    const int bid = blockIdx.x;
    if ((bid & 7) >= 2) return;        // dummy WG (placement trick)
    const int dir = bid & 7;           // 0 or 1
    const int wg  = bid >> 3;          // 0..15

    __shared__ unsigned h_pk[200];     // 400 halfs of h_prev
    __shared__ float part[16][28];
    unsigned short* hs = (unsigned short*)h_pk;
    const int tid = threadIdx.x;
    const int j0  = wg * RPW;
    const float* whh = dir ? whh_b : whh_f;
    const float* h0d = dir ? h0b : h0f;
    const float* c0d = dir ? c0b : c0f;

    const int w    = tid >> 6;         // wave 0..15
    const int lane = tid & 63;
    const int g    = w & 3;            // gate
    const int kq   = w >> 2;           // k-quarter (100 elems)
    const int half = lane & 1;         // k-split within quarter
    const int r    = lane >> 1;        // row within WG (active if r<25)
    const int jrow = j0 + (r < RPW ? r : RPW - 1);

    // one-time: 52 W_hh weights/thread, fp16-packed into 26 uints (spill-proof)
    unsigned wr[26];
    {
        const float2* wp = (const float2*)(whh + (size_t)(g * 400 + jrow) * 400 +
                                           kq * 100 + 48 * half);
#pragma unroll
        for (int i = 0; i < 26; ++i) {
            H2U cv; float2 f = wp[i];
            cv.hh = __floats2half2_rn(f.x, f.y);
            wr[i] = (half == 0 && i >= 24) ? 0u : cv.u;
        }
    }

    // pollers: tid 64..271 (waves 1-4), 16 producers x 13 dwords
    const bool is_poller = (tid >= 64 && tid < 272);
    const int pp = (tid - 64) / 13;    // producer block polled
    const int pd = (tid - 64) % 13;    // dword within block
    float c_prev = (tid < RPW) ? c0d[j0 + tid] : 0.f;

    // ring slot banks: live ("+v") across the whole step loop so stray
    // in-flight loads can only ever write these registers.
    unsigned sA0 = 0, sB0 = 0, sC0 = 0, sD0 = 0;
    unsigned sA1 = 0, sB1 = 0, sC1 = 0, sD1 = 0;

    for (int s = 0; s < 320; ++s) {
        const int row = dir ? (319 - s) : s;

        // gate prefetch (independent of h_prev, overlaps the poll)
        float gv0 = 0.f, gv1 = 0.f, gv2 = 0.f, gv3 = 0.f;
        if (tid < RPW) {
            const float* gx = gates + (size_t)row * NCOL + dir * GATES + j0 + tid;
            gv0 = gx[0]; gv1 = gx[400]; gv2 = gx[800]; gv3 = gx[1200];
        }

        if (s == 0) {
            if (tid < 100) {
                float4 f = ((const float4*)h0d)[tid];
                H2U a, b;
                a.hh = __floats2half2_rn(f.x, f.y);
                b.hh = __floats2half2_rn(f.z, f.w);
                ((uint2*)h_pk)[tid] = make_uint2(a.u, b.u);
            }
        } else if (is_poller && pp != wg) {
            const int rp = dir ? (row + 1) : (row - 1);
            const unsigned* srcS = ex + (((size_t)dir * GDW + pp) * SEQ + rp) * 16 + pd;
            unsigned res;
            unsigned long long execsave;
            if (s & 1) { POLL_RING(sA1, sB1, sC1, sD1); }
            else       { POLL_RING(sA0, sB0, sC0, sD0); }
            const int hb = pp * RPW + pd * 2;
            hs[hb] = (unsigned short)(res & 0xFFFFu);
            if (pd < 12) hs[hb + 1] = (unsigned short)(res >> 16);
        }
        // barrier 1: LDS-only drain (no vmcnt -> ring loads stay in flight)
        asm volatile("s_waitcnt lgkmcnt(0)" ::: "memory");
        __builtin_amdgcn_s_barrier();

        // partial dot: 52 halves via 13 ds_read_b64 + 26 v_dot2_f32_f16
        {
            const uint2* hp2 = (const uint2*)h_pk + kq * 25 + 12 * half;
            float acc = 0.f;
#pragma unroll
            for (int i = 0; i < 13; ++i) {
                uint2 hv2 = hp2[i];
                H2U w0, w1, x0, x1;
                w0.u = wr[2 * i]; w1.u = wr[2 * i + 1];
                x0.u = hv2.x;     x1.u = hv2.y;
                acc = __builtin_amdgcn_fdot2(w0.h, x0.h, acc, false);
                acc = __builtin_amdgcn_fdot2(w1.h, x1.h, acc, false);
            }
            acc += __shfl_xor(acc, 1, 64);
            if (half == 0 && r < RPW) part[w][r] = acc;
        }
        // barrier 2: LDS-only drain
        asm volatile("s_waitcnt lgkmcnt(0)" ::: "memory");
        __builtin_amdgcn_s_barrier();

        // activation + exchange store (wave 0 only)
        float hv = 0.f;
        if (tid < RPW) {
            float gi = gv0 + ((part[0][tid] + part[4][tid]) + (part[8][tid]  + part[12][tid]));
            float gf = gv1 + ((part[1][tid] + part[5][tid]) + (part[9][tid]  + part[13][tid]));
            float gg = gv2 + ((part[2][tid] + part[6][tid]) + (part[10][tid] + part[14][tid]));
            float go = gv3 + ((part[3][tid] + part[7][tid]) + (part[11][tid] + part[15][tid]));
            float iv = 1.f / (1.f + __expf(-gi));
            float fv = 1.f / (1.f + __expf(-gf));
            float ov = 1.f / (1.f + __expf(-go));
            float tg = 1.f - 2.f / (1.f + __expf(2.f * gg));
            c_prev = fv * c_prev + iv * tg;
            float tc = 1.f - 2.f / (1.f + __expf(2.f * c_prev));
            hv = ov * tc;
        }
        if (w == 0) {
            int i0 = 2 * lane     < 63 ? 2 * lane     : 63;
            int i1 = 2 * lane + 1 < 63 ? 2 * lane + 1 : 63;
            float xlo = __shfl(hv, i0, 64);
            float xhi = __shfl(hv, i1, 64);
            if (lane < 13) {                 // one private 64B line per step
                H2U pk;
                pk.hh = __floats2half2_rn(xlo, (2 * lane + 1 < RPW) ? xhi : 0.f);
                __hip_atomic_store(ex + (((size_t)dir * GDW + wg) * SEQ + row) * 16 + lane,
                                   pk.u, __ATOMIC_RELAXED, __HIP_MEMORY_SCOPE_AGENT);
            }
            if (tid < RPW) {                 // fp16 h for next GEMM + own-row LDS
                ah[(size_t)row * 800 + dir * 400 + j0 + tid] = (_Float16)hv;
                H2U o; o.hh = __floats2half2_rn(hv, 0.f);
                hs[RPW * wg + tid] = (unsigned short)(o.u & 0xFFFFu);
            }
        }
        // hazards: identical to R11/R12 (poll/act writes vs dot reads separated
        // by the two lgkmcnt-drained barriers; disjoint LDS ranges). safe.
    }
    // drain stray ring loads before endpgm
    asm volatile("s_waitcnt vmcnt(0)" ::: "memory");
}

// ---------------------------------------------------------------- fused scorer (+ border rows)
__global__ __launch_bounds__(256) void scores_kernel(
    const float* __restrict__ ab, const float* __restrict__ w2,
    const float* __restrict__ b2, float* __restrict__ out)
{
    if (blockIdx.y == 20) {              // border: row 0 / col 0
        int i = blockIdx.x * 256 + threadIdx.y * 16 + threadIdx.x;
        if (blockIdx.x < 2 && i < 321) {
            out[i]               = (i == 0) ? 1.f : 0.f;
            out[(size_t)i * 321] = (i == 0) ? 1.f : 0.f;
        }
        return;
    }
    __shared__ float a_s[16 * 132];
    __shared__ float b_s[16 * 132];
    __shared__ float w_s[128];
    const int tx = threadIdx.x, ty = threadIdx.y;
    const int tid = ty * 16 + tx;
    const int n0 = blockIdx.y * 16, d0 = blockIdx.x * 16;
    float acc = 0.f;
    for (int kc = 0; kc < 1600; kc += 128) {
        for (int i = tid; i < 16 * 128; i += 256) {
            int r = i >> 7, c = i & 127;
            a_s[r * 132 + c] = ab[(size_t)(n0 + r) * NCOL + kc + c];
            b_s[r * 132 + c] = ab[(size_t)(d0 + r) * NCOL + 1600 + kc + c];
        }
        if (tid < 128) w_s[tid] = w2[kc + tid];
        __syncthreads();
#pragma unroll
        for (int k = 0; k < 128; k += 4) {
            float4 av = *(const float4*)&a_s[ty * 132 + k];
            float4 bv = *(const float4*)&b_s[tx * 132 + k];
            float4 wv = *(const float4*)&w_s[k];
            acc += fmaxf(av.x + bv.x, 0.f) * wv.x;
            acc += fmaxf(av.y + bv.y, 0.f) * wv.y;
            acc += fmaxf(av.z + bv.z, 0.f) * wv.z;
            acc += fmaxf(av.w + bv.w, 0.f) * wv.w;
        }
        __syncthreads();
    }
    int n = n0 + ty, d = d0 + tx;
    out[(size_t)(n + 1) * 321 + (d + 1)] = (n == d) ? 0.f : (acc + b2[0]);
}

// ---------------------------------------------------------------- launcher
extern "C" void kernel_launch(void* const* d_in, const int* in_sizes, int n_in,
                              void* d_out, int out_size, void* d_ws, size_t ws_size,
                              hipStream_t stream)
{
    const int*   words    = (const int*)d_in[0];
    const int*   tags     = (const int*)d_in[1];
    const float* wemb     = (const float*)d_in[3];
    const float* temb     = (const float*)d_in[4];
    const float* h0       = (const float*)d_in[5];
    const float* c0       = (const float*)d_in[6];
    const float* w_ih_l0  = (const float*)d_in[7];
    const float* w_hh_l0  = (const float*)d_in[8];
    const float* b_ih_l0  = (const float*)d_in[9];
    const float* b_hh_l0  = (const float*)d_in[10];
    const float* w_ih_l0r = (const float*)d_in[11];
    const float* w_hh_l0r = (const float*)d_in[12];
    const float* b_ih_l0r = (const float*)d_in[13];
    const float* b_hh_l0r = (const float*)d_in[14];
    const float* w_ih_l1  = (const float*)d_in[15];
    const float* w_hh_l1  = (const float*)d_in[16];
    const float* b_ih_l1  = (const float*)d_in[17];
    const float* b_hh_l1  = (const float*)d_in[18];
    const float* w_ih_l1r = (const float*)d_in[19];
    const float* w_hh_l1r = (const float*)d_in[20];
    const float* b_ih_l1r = (const float*)d_in[21];
    const float* b_hh_l1r = (const float*)d_in[22];
    const float* mlp_w1   = (const float*)d_in[23];
    const float* mlp_b1   = (const float*)d_in[24];
    const float* mlp_w2   = (const float*)d_in[25];
    const float* mlp_b2   = (const float*)d_in[26];
    float* out = (float*)d_out;

    float* ws      = (float*)d_ws;
    float*    gates  = ws;                              // 320*3200 = 1,024,000 f32
    float*    biasL0 = ws + 1024000;
    float*    biasL1 = ws + 1027200;
    float*    biasAB = ws + 1030400;
    unsigned* ex     = (unsigned*)(ws + 1033600);       // 163,840 u32 used (region reserved to +327,680)
    _Float16* Ah0    = (_Float16*)(ws + 1361280);       // 320*416 halves
    _Float16* Ah1    = (_Float16*)(ws + 1427840);       // 320*800 halves
    _Float16* Ah2    = (_Float16*)(ws + 1555840);       // 320*800 halves
    _Float16* BhA    = (_Float16*)(ws + 1683840);       // up to 3200*800 halves
    _Float16* BhB    = (_Float16*)(ws + 2963840);       // 3200*800 halves

    // sentinel-fill the exchange plane (data doubles as ready flag)
    hipMemsetAsync(ex, 0xFF, 163840u * 4, stream);

    prep_kernel<<<5733, 256, 0, stream>>>(
        words, tags, wemb, temb, Ah0,
        b_ih_l0, b_hh_l0, b_ih_l0r, b_hh_l0r,
        b_ih_l1, b_hh_l1, b_ih_l1r, b_hh_l1r,
        mlp_b1, biasL0, biasL1, biasAB, w_ih_l0, w_ih_l0r, BhA);

    gemm_f16<<<dim3(50, 10), 256, 0, stream>>>(Ah0, 416, BhA, biasL0, gates);
    cvt2_kernel<<<20000, 256, 0, stream>>>(w_ih_l1, w_ih_l1r, BhB, mlp_w1, BhA);
    lstm_layer<<<128, 1024, 0, stream>>>(gates, w_hh_l0, w_hh_l0r,
                                         h0, h0 + 400, c0, c0 + 400, ex, Ah1);
    // re-sentinel for layer 1 (stream-ordered after lstm L0)
    hipMemsetAsync(ex, 0xFF, 163840u * 4, stream);
    gemm_f16<<<dim3(50, 10), 256, 0, stream>>>(Ah1, 800, BhB, biasL1, gates);
    lstm_layer<<<128, 1024, 0, stream>>>(gates, w_hh_l1, w_hh_l1r,
                                         h0 + 800, h0 + 1200, c0 + 800, c0 + 1200,
                                         ex, Ah2);
    gemm_f16<<<dim3(50, 10), 256, 0, stream>>>(Ah2, 800, BhA, biasAB, gates);

    scores_kernel<<<dim3(20, 21), dim3(16, 16), 0, stream>>>(gates, mlp_w2, mlp_b2, out);
}